// Round 1
// baseline (100.937 us; speedup 1.0000x reference)
//
#include <hip/hip_runtime.h>
#include <stdint.h>

// ---------------------------------------------------------------------------
// NT-Xent loss, B=8 S=512 D=128  ->  N=4096, 2N=8192 rows, K=128.
// loss = mean_i( -pos_i + log(sum_{j!=i} exp(sim_ij)) ),  sim = z_n z_n^T / T
//
// v2: exploit sim symmetry. Only super-diagonal 128x128 tiles (J >= I) are
// computed: 2080 tiles instead of 4096. Off-diagonal tiles (I < J) emit BOTH
// row sums (c-lane shuffle reduce, as before) and column sums (q-group
// shuffle reduce -> LDS colacc -> one atomicAdd per column). Diagonal tiles
// (I == J) are computed fully (they are their own transpose) with exact
// diagonal exclusion, row sums only. Halves MFMA/exp2/LDS-read work.
//
//  k1: normalize rows (fp32), compute pos_half in fp32, store z_n * SCALE as
//      bf16 where SCALE^2 = log2(e)/T, so the MFMA accumulator is sim*log2e
//      and exp(sim) == exp2(acc) == one v_exp_f32.   Also zeroes rowsum.
//  k2: symmetric Gram + exp row/col sums (see above). 128-thread blocks,
//      2 waves x 64 rows, B tiles (64 cols x 128k) staged in LDS (+16B pad).
//  k3: loss = (sum_i log(rowsum_i) - 2*sum pos_half) / 8192.
// No max-subtraction needed: logits in [-14.3,14.3], sums < 1.3e10 (fp32-safe).
// ---------------------------------------------------------------------------

#define TOTAL   8192
#define NHALF   4096
#define DK      128
#define TEMP_INV 14.285714285714286f
#define SCALE    4.539816f      // sqrt(log2(e)/0.07); SCALE^2 = 20.609929

#define TILE    128                       // square tile edge
#define TILES   (TOTAL / TILE)            // 64
#define NBLK    (TILES * (TILES + 1) / 2) // 2080 super-diagonal tiles
#define BN      64                        // cols staged per LDS stage
#define NSTAGE  (TILE / BN)               // 2

typedef short  bf16x8  __attribute__((ext_vector_type(8)));
typedef float  floatx4 __attribute__((ext_vector_type(4)));

#if __has_builtin(__builtin_amdgcn_exp2f)
#define EXP2(x) __builtin_amdgcn_exp2f(x)
#else
#define EXP2(x) exp2f(x)
#endif

__device__ __forceinline__ uint32_t f2bf(float f) {
  uint32_t u = __float_as_uint(f);
  return (u + 0x7fffu + ((u >> 16) & 1u)) >> 16;   // RNE; inputs finite
}
__device__ __forceinline__ uint32_t pack2bf(float lo, float hi) {
  return f2bf(lo) | (f2bf(hi) << 16);
}

// --------------------------- kernel 1: normalize ---------------------------
// grid 1024 x 256. Each wave handles one i (both z_i and z_j rows).
__global__ __launch_bounds__(256) void ntx_norm(
    const float* __restrict__ zi, const float* __restrict__ zj,
    uint32_t* __restrict__ zn,   // packed 2xbf16, [TOTAL][64]
    float* __restrict__ pos,     // [NHALF]
    float* __restrict__ rowsum)  // [TOTAL], zeroed here
{
  const int t = threadIdx.x;
  if (blockIdx.x < 32) rowsum[blockIdx.x * 256 + t] = 0.0f;

  const int wave = t >> 6, lane = t & 63;
  const int i = blockIdx.x * 4 + wave;

  const float2 vi = *(const float2*)(zi + (size_t)i * DK + lane * 2);
  const float2 vj = *(const float2*)(zj + (size_t)i * DK + lane * 2);
  float ssi = vi.x * vi.x + vi.y * vi.y;
  float ssj = vj.x * vj.x + vj.y * vj.y;
  float dij = vi.x * vj.x + vi.y * vj.y;
#pragma unroll
  for (int m = 1; m <= 32; m <<= 1) {
    ssi += __shfl_xor(ssi, m, 64);
    ssj += __shfl_xor(ssj, m, 64);
    dij += __shfl_xor(dij, m, 64);
  }
  const float invi = 1.0f / fmaxf(sqrtf(ssi), 1e-12f);
  const float invj = 1.0f / fmaxf(sqrtf(ssj), 1e-12f);

  zn[(size_t)i * 64 + lane] =
      pack2bf(vi.x * invi * SCALE, vi.y * invi * SCALE);
  zn[(size_t)(i + NHALF) * 64 + lane] =
      pack2bf(vj.x * invj * SCALE, vj.y * invj * SCALE);
  if (lane == 0) pos[i] = dij * invi * invj * TEMP_INV;
}

// ---------------- kernel 2: symmetric Gram + exp row/col sums --------------
// grid NBLK x 128. Linear block id -> upper-triangular tile (I, J), J >= I.
__global__ __launch_bounds__(128, 3) void ntx_gemm(
    const uint16_t* __restrict__ z,   // [TOTAL][DK] bf16 (scaled)
    float* __restrict__ rowsum)
{
  __shared__ uint4 lb4[BN * 17];      // 64 rows x (256B data + 16B pad)
  __shared__ float colacc[2][TILE];   // per-wave column partial sums

  // map linear block id -> (I, J) with J >= I  (row-major upper triangle)
  int I = 0, rem = (int)blockIdx.x, span = TILES;
  while (rem >= span) { rem -= span; --span; ++I; }
  const int J = I + rem;
  const bool isdiag = (I == J);

  const int t = threadIdx.x;
  const int wave = t >> 6, lane = t & 63;
  const int q = lane >> 4, c = lane & 15;
  const int i0 = I * TILE;
  const int j0 = J * TILE;
  const int rowbase = i0 + wave * 64;

  // A fragments: 4 strips x 4 k-steps, held in registers for the whole block.
  // A[m=c][k=q*8+j] -> z[rowbase+s*16+c][kk*32+q*8 .. +8]
  bf16x8 afrag[4][4];
#pragma unroll
  for (int s = 0; s < 4; ++s) {
    const uint16_t* ap = z + (size_t)(rowbase + s * 16 + c) * DK + q * 8;
#pragma unroll
    for (int kk = 0; kk < 4; ++kk)
      afrag[s][kk] = *(const bf16x8*)(ap + kk * 32);
  }

  float runsum[4][4];
#pragma unroll
  for (int s = 0; s < 4; ++s)
#pragma unroll
    for (int r = 0; r < 4; ++r) runsum[s][r] = 0.0f;

  const int ch = t & 15;     // 16B chunk within a row
  const int r0 = t >> 4;     // staging row 0..7

  for (int st = 0; st < NSTAGE; ++st) {
    const int jst = j0 + st * BN;
    __syncthreads();   // previous stage's reads done before overwrite
#pragma unroll
    for (int p = 0; p < 8; ++p) {
      const int r = r0 + p * 8;
      uint4 v = *(const uint4*)(z + (size_t)(jst + r) * DK + ch * 8);
      lb4[r * 17 + ch] = v;
    }
    __syncthreads();

#pragma unroll
    for (int jt = 0; jt < BN / 16; ++jt) {
      // B[k=q*8+j][n=c] -> lds row (jt*16+c), bytes kk*64 + q*16
      bf16x8 bfrag[4];
#pragma unroll
      for (int kk = 0; kk < 4; ++kk)
        bfrag[kk] = *(const bf16x8*)&lb4[(jt * 16 + c) * 17 + kk * 4 + q];
      const int jc = jst + jt * 16;    // col = jc + c

      float colv = 0.0f;
#pragma unroll
      for (int s = 0; s < 4; ++s) {
        floatx4 acc = {0.0f, 0.0f, 0.0f, 0.0f};
#pragma unroll
        for (int kk = 0; kk < 4; ++kk)
          acc = __builtin_amdgcn_mfma_f32_16x16x32_bf16(afrag[s][kk],
                                                        bfrag[kk], acc,
                                                        0, 0, 0);
        const int rb = rowbase + s * 16;   // row = rb + q*4 + r
        if (!isdiag) {                     // off-diagonal block: row+col sums
#pragma unroll
          for (int r = 0; r < 4; ++r) {
            float e = EXP2(acc[r]);
            runsum[s][r] += e;
            colv += e;
          }
        } else if (jc == rb) {             // diagonal tile (wave-uniform)
#pragma unroll
          for (int r = 0; r < 4; ++r) {
            float e = EXP2(acc[r]);
            runsum[s][r] += (q * 4 + r == c) ? 0.0f : e;
          }
        } else {                           // diag block, off-diag tile
#pragma unroll
          for (int r = 0; r < 4; ++r) runsum[s][r] += EXP2(acc[r]);
        }
      }

      if (!isdiag) {
        // column sums over this wave's 64 rows: combine the 4 q-groups
        colv += __shfl_xor(colv, 16, 64);
        colv += __shfl_xor(colv, 32, 64);
        if (lane < 16)
          colacc[wave][st * BN + jt * 16 + lane] = colv;  // each col once
      }
    }
  }

  // row sums: reduce across the 16 c-lanes (same q)
#pragma unroll
  for (int s = 0; s < 4; ++s)
#pragma unroll
    for (int r = 0; r < 4; ++r) {
      float v = runsum[s][r];
      v += __shfl_xor(v, 1, 64);
      v += __shfl_xor(v, 2, 64);
      v += __shfl_xor(v, 4, 64);
      v += __shfl_xor(v, 8, 64);
      runsum[s][r] = v;
    }
  if (c == 0) {
#pragma unroll
    for (int s = 0; s < 4; ++s)
#pragma unroll
      for (int r = 0; r < 4; ++r)
        atomicAdd(&rowsum[rowbase + s * 16 + q * 4 + r], runsum[s][r]);
  }

  // column sums -> transpose rows (off-diagonal blocks only)
  __syncthreads();
  if (!isdiag && t < TILE)
    atomicAdd(&rowsum[j0 + t], colacc[0][t] + colacc[1][t]);
}

// --------------------------- kernel 3: finalize ----------------------------
__global__ __launch_bounds__(1024) void ntx_final(
    const float* __restrict__ rowsum, const float* __restrict__ pos,
    float* __restrict__ out)
{
  const int t = threadIdx.x;
  float acc = 0.0f;
  for (int r = t; r < TOTAL; r += 1024) acc += __logf(rowsum[r]);
  for (int r = t; r < NHALF; r += 1024) acc -= 2.0f * pos[r];
#pragma unroll
  for (int m = 1; m <= 32; m <<= 1) acc += __shfl_xor(acc, m, 64);
  __shared__ float red[16];
  const int wave = t >> 6, lane = t & 63;
  if (lane == 0) red[wave] = acc;
  __syncthreads();
  if (t == 0) {
    float s = 0.0f;
#pragma unroll
    for (int w = 0; w < 16; ++w) s += red[w];
    out[0] = s / (float)TOTAL;
  }
}

// ---------------------------------------------------------------------------
extern "C" void kernel_launch(void* const* d_in, const int* in_sizes, int n_in,
                              void* d_out, int out_size, void* d_ws,
                              size_t ws_size, hipStream_t stream) {
  const float* zi = (const float*)d_in[0];
  const float* zj = (const float*)d_in[1];
  float* out = (float*)d_out;

  char* ws = (char*)d_ws;
  uint16_t* zn     = (uint16_t*)ws;                        // 2 MB bf16
  float*    rowsum = (float*)(ws + (size_t)TOTAL * DK * 2);          // 32 KB
  float*    pos    = (float*)(ws + (size_t)TOTAL * DK * 2 + TOTAL * 4); // 16 KB

  ntx_norm<<<dim3(NHALF / 4), dim3(256), 0, stream>>>(zi, zj, (uint32_t*)zn,
                                                      pos, rowsum);
  ntx_gemm<<<dim3(NBLK), dim3(128), 0, stream>>>(zn, rowsum);
  ntx_final<<<dim3(1), dim3(1024), 0, stream>>>(rowsum, pos, out);
}